// Round 15
// baseline (53.441 us; speedup 1.0000x reference)
//
#include <hip/hip_runtime.h>
#include <stdint.h>

// Problem constants
#define B_ 4
#define T_ 1024
#define D_ 1024
#define H_ 2048
#define E_ 8

// Fire-and-forget global->LDS staging, 16B/lane. LDS dest wave-uniform
// (HW adds lane*16); global source is per-lane.
__device__ __forceinline__ void stage16(const float* g, float* l) {
    __builtin_amdgcn_global_load_lds(
        (const __attribute__((address_space(1))) uint32_t*)g,
        (__attribute__((address_space(3))) uint32_t*)l, 16, 0, 0);
}

// --------------------------------------------------------------------------
// Kernel AB (merged, no cross-block sync): block = (expert e, j-chunk of 32).
// Phase 1: w2sum_part[j] = sum_d w2[e, j, d] for the 32-row chunk — exact
//   kernel-A rolling pipeline (8 tiles x 4 rows, 3-buf, counted vmcnt).
// Phase 2: for ALL d: vT[d*E+e] += dot(w1[e, d, j0:j0+32], ws_part).
//   w1 chunk = 128 B/row; staged via global_load_lds per-lane-source into
//   linear LDS tiles (32 rows x 32 floats = 4 KB/wave-tile). Row sums kept
//   in REGISTERS p[8][4]; all atomics issued after the final vmcnt(0) so
//   the counted-vmcnt arithmetic stays exact. atomicAdd is device-scope.
// 512 blocks x 256 thr; 64 chunks/expert. vT/cbuf must be pre-zeroed.
// --------------------------------------------------------------------------
__global__ __launch_bounds__(256) void ab_kernel(
    const float* __restrict__ w1, const float* __restrict__ b1,
    const float* __restrict__ w2, const float* __restrict__ b2,
    float* __restrict__ vT, float* __restrict__ cbuf)
{
    __shared__ float buf[3][4096];                 // 48 KB, reused by both phases
    __shared__ float wssum[32];                    // w2sum_part for this chunk
    const int bid = blockIdx.x;
    const int e   = bid >> 6;                      // 64 chunks per expert
    const int j0  = (bid & 63) * 32;               // j-chunk base
    const int wid = threadIdx.x >> 6, lane = threadIdx.x & 63;

    // ================= Phase 1: w2 chunk row sums =================
    {
        const float* src = w2 + ((size_t)(e * H_ + j0) + wid) * D_ + lane * 4;
#define P1_STAGE(k) { const float* s_ = src + (size_t)(k) * 4 * D_;           \
                      float* d_ = &buf[(k) % 3][wid * 1024];                  \
                      stage16(s_, d_);         stage16(s_ + 256, d_ + 256);   \
                      stage16(s_ + 512, d_ + 512); stage16(s_ + 768, d_ + 768); }
        P1_STAGE(0); P1_STAGE(1);
        float accs[8];
#pragma unroll
        for (int k = 0; k < 8; ++k) {
            if (k < 7) asm volatile("s_waitcnt vmcnt(4)" ::: "memory");
            else       asm volatile("s_waitcnt vmcnt(0)" ::: "memory");
            if (k < 6) P1_STAGE(k + 2);
            const float* row = &buf[k % 3][wid * 1024];
            float acc = 0.f;
#pragma unroll
            for (int j = 0; j < 4; ++j) {
                float4 a = *(const float4*)&row[j * 256 + lane * 4];
                acc += a.x + a.y + a.z + a.w;
            }
#pragma unroll
            for (int off = 32; off >= 1; off >>= 1) acc += __shfl_xor(acc, off, 64);
            accs[k] = acc;
        }
#undef P1_STAGE
        if (lane == 0) {
#pragma unroll
            for (int k = 0; k < 8; ++k) wssum[wid + k * 4] = accs[k];  // local j = wid + 4k
        }
    }
    __syncthreads();   // phase-1 fully drained; wssum visible; buf reusable

    // ================= Phase 2: w1 chunk -> vT accumulation =================
    // lane's j-slice: jpart = (lane&7)*4 .. +3 ; row group m = lane>>3
    const float4 wsv = *(const float4*)&wssum[(lane & 7) * 4];
    const float* w1base = w1 + (size_t)e * D_ * H_ + j0 + (lane & 7) * 4;

#define P2_STAGE(t) {                                                          \
        const int rb_ = wid * 256 + (t) * 32;                                  \
        float* d_ = &buf[(t) % 3][wid * 1024];                                 \
        const float* s_ = w1base + (size_t)(rb_ + (lane >> 3)) * H_;           \
        stage16(s_,               d_);                                         \
        stage16(s_ + (size_t) 8 * H_, d_ + 256);                               \
        stage16(s_ + (size_t)16 * H_, d_ + 512);                               \
        stage16(s_ + (size_t)24 * H_, d_ + 768); }

    P2_STAGE(0); P2_STAGE(1);
    float p[8][4];
#pragma unroll
    for (int t = 0; t < 8; ++t) {
        if (t < 7) asm volatile("s_waitcnt vmcnt(4)" ::: "memory");
        else       asm volatile("s_waitcnt vmcnt(0)" ::: "memory");
        if (t < 6) P2_STAGE(t + 2);
        const float* dat = &buf[t % 3][wid * 1024];
#pragma unroll
        for (int s = 0; s < 4; ++s) {
            float4 a = *(const float4*)&dat[s * 256 + lane * 4];
            float v = a.x * wsv.x + a.y * wsv.y + a.z * wsv.z + a.w * wsv.w;
            // reduce over jpart lanes (bits 0..2)
            v += __shfl_xor(v, 1, 64);
            v += __shfl_xor(v, 2, 64);
            v += __shfl_xor(v, 4, 64);
            p[t][s] = v;
        }
    }
#undef P2_STAGE

    // all VMEM staging drained -> now issue the atomics (device-scope)
    if ((lane & 7) == 0) {
        const int m = lane >> 3;
#pragma unroll
        for (int t = 0; t < 8; ++t)
#pragma unroll
            for (int s = 0; s < 4; ++s)
                atomicAdd(&vT[(size_t)(wid * 256 + t * 32 + s * 8 + m) * E_ + e],
                          p[t][s]);
    }

    // c[e] contributions: b1 dot ws_part (every block) + b2 sum (first chunk)
    if (wid == 0) {
        float tt = (lane < 32) ? b1[(size_t)e * H_ + j0 + lane] * wssum[lane] : 0.f;
#pragma unroll
        for (int off = 32; off >= 1; off >>= 1) tt += __shfl_xor(tt, off, 64);
        if (lane == 0) atomicAdd(&cbuf[e], tt);
    }
    if ((bid & 63) == 0 && wid == 1) {
        float tt = 0.f;
        for (int k = lane; k < D_; k += 64) tt += b2[(size_t)e * D_ + k];
#pragma unroll
        for (int off = 32; off >= 1; off >>= 1) tt += __shfl_xor(tt, off, 64);
        if (lane == 0) atomicAdd(&cbuf[e], tt);
    }
}

// --------------------------------------------------------------------------
// Kernel C: LDS-staged gating (R14 structure, higher occupancy + shared
// reads). 512 blocks x 256 thr; block stages wg (32 KB) + vT (32 KB) into
// LDS once (64 KB -> 2 blocks/CU), then 4 waves x 2 tokens each, both
// tokens of a wave SHARING each LDS read (half the LDS traffic, 2x ILP).
// Conflict-free reads: lane l -> 16B unit at rows (l>>1), col group (l&1);
// wave reads 1 KB contiguous. Butterfly over lane bits [5:1].
// --------------------------------------------------------------------------
__global__ __launch_bounds__(256) void token_kernel(
    const float* __restrict__ x,  const float* __restrict__ wg,
    const float* __restrict__ vT, const float* __restrict__ cbuf,
    float* __restrict__ sbuf)
{
    __shared__ float wgl[D_ * E_];   // 32 KB  [d][e]
    __shared__ float vtl[D_ * E_];   // 32 KB  [d][e]
    const int wid = threadIdx.x >> 6, lane = threadIdx.x & 63;

#pragma unroll
    for (int r = 0; r < 8; ++r) {
        int base = r * 1024 + wid * 256;
        stage16(wg + base + lane * 4, wgl + base);
        stage16(vT + base + lane * 4, vtl + base);
    }
    asm volatile("s_waitcnt vmcnt(0)" ::: "memory");
    __syncthreads();

    const int half = lane & 1;       // 0 -> expert cols 0-3, 1 -> cols 4-7
    const int rrow = lane >> 1;      // row residue mod 32

    const int nA = blockIdx.x * 8 + wid * 2;
    const float* xga = x + (size_t)nA * D_ + rrow;
    const float* xgb = xga + D_;

    float agA[4] = {0,0,0,0}, avA[4] = {0,0,0,0};
    float agB[4] = {0,0,0,0}, avB[4] = {0,0,0,0};

#pragma unroll
    for (int k = 0; k < 32; ++k) {
        float xa = xga[32 * k];
        float xb = xgb[32 * k];
        const int o = (32 * k + rrow) * 8 + half * 4;
        float4 w4 = *(const float4*)&wgl[o];
        float4 v4 = *(const float4*)&vtl[o];
        agA[0] += xa * w4.x; agA[1] += xa * w4.y; agA[2] += xa * w4.z; agA[3] += xa * w4.w;
        avA[0] += xa * v4.x; avA[1] += xa * v4.y; avA[2] += xa * v4.z; avA[3] += xa * v4.w;
        agB[0] += xb * w4.x; agB[1] += xb * w4.y; agB[2] += xb * w4.z; agB[3] += xb * w4.w;
        avB[0] += xb * v4.x; avB[1] += xb * v4.y; avB[2] += xb * v4.z; avB[3] += xb * v4.w;
    }

#pragma unroll
    for (int off = 2; off <= 32; off <<= 1) {
#pragma unroll
        for (int q = 0; q < 4; ++q) {
            agA[q] += __shfl_xor(agA[q], off, 64);
            avA[q] += __shfl_xor(avA[q], off, 64);
            agB[q] += __shfl_xor(agB[q], off, 64);
            avB[q] += __shfl_xor(avB[q], off, 64);
        }
    }
    // lane 1 holds expert cols 4-7 of both tokens
    float gA4 = __shfl(agA[0], 1, 64), gA5 = __shfl(agA[1], 1, 64),
          gA6 = __shfl(agA[2], 1, 64), gA7 = __shfl(agA[3], 1, 64);
    float hA4 = __shfl(avA[0], 1, 64), hA5 = __shfl(avA[1], 1, 64),
          hA6 = __shfl(avA[2], 1, 64), hA7 = __shfl(avA[3], 1, 64);
    float gB4 = __shfl(agB[0], 1, 64), gB5 = __shfl(agB[1], 1, 64),
          gB6 = __shfl(agB[2], 1, 64), gB7 = __shfl(agB[3], 1, 64);
    float hB4 = __shfl(avB[0], 1, 64), hB5 = __shfl(avB[1], 1, 64),
          hB6 = __shfl(avB[2], 1, 64), hB7 = __shfl(avB[3], 1, 64);

    if (lane == 0) {
#pragma unroll
        for (int tok = 0; tok < 2; ++tok) {
            float lg[E_], dv[E_];
            if (tok == 0) {
                lg[0]=agA[0]; lg[1]=agA[1]; lg[2]=agA[2]; lg[3]=agA[3];
                lg[4]=gA4;    lg[5]=gA5;    lg[6]=gA6;    lg[7]=gA7;
                dv[0]=avA[0]; dv[1]=avA[1]; dv[2]=avA[2]; dv[3]=avA[3];
                dv[4]=hA4;    dv[5]=hA5;    dv[6]=hA6;    dv[7]=hA7;
            } else {
                lg[0]=agB[0]; lg[1]=agB[1]; lg[2]=agB[2]; lg[3]=agB[3];
                lg[4]=gB4;    lg[5]=gB5;    lg[6]=gB6;    lg[7]=gB7;
                dv[0]=avB[0]; dv[1]=avB[1]; dv[2]=avB[2]; dv[3]=avB[3];
                dv[4]=hB4;    dv[5]=hB5;    dv[6]=hB6;    dv[7]=hB7;
            }
            // top-2, tie -> lower index (jax.lax.top_k semantics)
            float m0 = lg[0]; int i0 = 0;
#pragma unroll
            for (int q = 1; q < E_; ++q) if (lg[q] > m0) { m0 = lg[q]; i0 = q; }
            float m1 = -3.0e38f; int i1 = 0;
#pragma unroll
            for (int q = 0; q < E_; ++q) if (q != i0 && lg[q] > m1) { m1 = lg[q]; i1 = q; }
            float dv0 = 0.f, dv1 = 0.f, c0v = 0.f, c1v = 0.f;
#pragma unroll
            for (int q = 0; q < E_; ++q) {
                if (q == i0) { dv0 += dv[q]; c0v += cbuf[q]; }
                if (q == i1) { dv1 += dv[q]; c1v += cbuf[q]; }
            }
            float g1w = 1.f / (1.f + expf(m0 - m1));
            sbuf[nA + tok] = (1.f - g1w) * (dv0 + c0v) + g1w * (dv1 + c1v);
        }
    }
}

// --------------------------------------------------------------------------
// Kernel D (round-8 verbatim): out[b,t] = s[b,t] - logsumexp_t(s[b,:]).
// One block, 4 waves, wave per batch row; 16 values per lane.
// --------------------------------------------------------------------------
__global__ __launch_bounds__(256) void lsm_kernel(const float* __restrict__ s,
                                                  float* __restrict__ out) {
    int brow = threadIdx.x >> 6;
    int lane = threadIdx.x & 63;
    const float* row = s + (size_t)brow * T_;
    float vals[16];
    float mx = -3.0e38f;
#pragma unroll
    for (int k = 0; k < 16; ++k) {
        vals[k] = row[lane + 64 * k];
        mx = fmaxf(mx, vals[k]);
    }
#pragma unroll
    for (int off = 32; off >= 1; off >>= 1) mx = fmaxf(mx, __shfl_xor(mx, off, 64));
    float sm = 0.f;
#pragma unroll
    for (int k = 0; k < 16; ++k) sm += expf(vals[k] - mx);
#pragma unroll
    for (int off = 32; off >= 1; off >>= 1) sm += __shfl_xor(sm, off, 64);
    float lse = mx + logf(sm);
#pragma unroll
    for (int k = 0; k < 16; ++k) out[(size_t)brow * T_ + lane + 64 * k] = vals[k] - lse;
}

// ---------------------------------------------------------------------------
extern "C" void kernel_launch(void* const* d_in, const int* in_sizes, int n_in,
                              void* d_out, int out_size, void* d_ws, size_t ws_size,
                              hipStream_t stream) {
    const float* x  = (const float*)d_in[0];   // [B, T, D]
    const float* wg = (const float*)d_in[1];   // [D, E]
    const float* w1 = (const float*)d_in[2];   // [E, D, H]
    const float* b1 = (const float*)d_in[3];   // [E, H]
    const float* w2 = (const float*)d_in[4];   // [E, H, D]
    const float* b2 = (const float*)d_in[5];   // [E, D]
    float* out = (float*)d_out;                // [B, T]

    float* ws   = (float*)d_ws;
    float* vT   = ws;                          // D*E = 8192 floats ([d][e])
    float* cbuf = ws + 8192;                   // E
    float* sbuf = ws + 8200;                   // N = 4096

    // zero the accumulation targets (vT + cbuf, contiguous) each launch
    hipMemsetAsync(vT, 0, (8192 + 8) * sizeof(float), stream);

    // AB: 8 experts x 64 j-chunks -> 512 blocks, no cross-block sync
    ab_kernel<<<dim3(512), dim3(256), 0, stream>>>(w1, b1, w2, b2, vT, cbuf);
    // C: 4096 tokens, 8/block, wg+vT LDS-staged -> 512 blocks (2 blocks/CU)
    token_kernel<<<dim3(512), dim3(256), 0, stream>>>(x, wg, vT, cbuf, sbuf);
    // D: log-softmax over T per batch row, single block
    lsm_kernel<<<dim3(1), dim3(256), 0, stream>>>(sbuf, out);
}

// Round 16
// 38.600 us; speedup vs baseline: 1.3845x; 1.3845x over previous
//
#include <hip/hip_runtime.h>
#include <stdint.h>

// Problem constants
#define B_ 4
#define T_ 1024
#define D_ 1024
#define H_ 2048
#define E_ 8

// Fire-and-forget global->LDS staging, 16B/lane. LDS dest wave-uniform.
__device__ __forceinline__ void stage16(const float* g, float* l) {
    __builtin_amdgcn_global_load_lds(
        (const __attribute__((address_space(1))) uint32_t*)g,
        (__attribute__((address_space(3))) uint32_t*)l, 16, 0, 0);
}

// --------------------------------------------------------------------------
// Kernel A (round-8 champion, verbatim): w2sum[r] = sum_d w2_flat[r, d].
// 512 blocks x 256 thr; block = 32 rows = 8 tiles of 4 rows, triple-buffered
// rolling global_load_lds pipeline, wave-private (no barriers).
// --------------------------------------------------------------------------
__global__ __launch_bounds__(256) void w2sum_kernel(const float* __restrict__ w2,
                                                    float* __restrict__ w2sum) {
    __shared__ float buf[3][4 * D_];                   // 48 KB
    const int wid = threadIdx.x >> 6, lane = threadIdx.x & 63;
    const float* src = w2 + ((size_t)blockIdx.x * 32 + wid) * D_ + lane * 4;

#define A_STAGE(k)                                                        \
    {                                                                     \
        const float* s_ = src + (size_t)(k) * 4 * D_;                     \
        float* d_ = &buf[(k) % 3][wid * D_];                              \
        stage16(s_,       d_);       stage16(s_ + 256, d_ + 256);         \
        stage16(s_ + 512, d_ + 512); stage16(s_ + 768, d_ + 768);         \
    }

    A_STAGE(0); A_STAGE(1);
    float accs[8];
#pragma unroll
    for (int k = 0; k < 8; ++k) {
        if (k < 7) asm volatile("s_waitcnt vmcnt(4)" ::: "memory");
        else       asm volatile("s_waitcnt vmcnt(0)" ::: "memory");
        if (k < 6) A_STAGE(k + 2);
        const float* row = &buf[k % 3][wid * D_];
        float acc = 0.f;
#pragma unroll
        for (int j = 0; j < 4; ++j) {
            float4 a = *(const float4*)&row[j * 256 + lane * 4];
            acc += a.x + a.y + a.z + a.w;
        }
#pragma unroll
        for (int off = 32; off >= 1; off >>= 1) acc += __shfl_xor(acc, off, 64);
        accs[k] = acc;
    }
#undef A_STAGE
    if (lane == 0) {
        const int r0 = blockIdx.x * 32 + wid;
#pragma unroll
        for (int k = 0; k < 8; ++k) w2sum[r0 + k * 4] = accs[k];
    }
}

// --------------------------------------------------------------------------
// Kernel B (round-8 champion, verbatim): vT[d*E + e] = dot(w1[e,d,:],
// w2sum[e,:]). 512 blocks x 256 thr; block = expert bid>>6, rows
// d0=(bid&63)*16 as 4 tiles of 4 rows, double-buffered (64 KB). w2sum[e]
// fragment in 8 float4 regs (cached; A->B boundary provides coherence).
// --------------------------------------------------------------------------
__global__ __launch_bounds__(256) void v_build_kernel(const float* __restrict__ w1,
                                                      const float* __restrict__ w2sum,
                                                      const float* __restrict__ b1,
                                                      const float* __restrict__ b2,
                                                      float* __restrict__ vT,
                                                      float* __restrict__ c) {
    __shared__ float buf[2][4 * H_];                   // 64 KB
    const int bid = blockIdx.x;
    const int e   = bid >> 6;                          // 64 blocks/expert
    const int d0  = (bid & 63) * 16;
    const int wid = threadIdx.x >> 6, lane = threadIdx.x & 63;
    const float* src = w1 + ((size_t)e * D_ + d0 + wid) * H_ + lane * 4;

    const float4* wsp = (const float4*)(w2sum + (size_t)e * H_) + lane;
    float4 s0 = wsp[0],   s1 = wsp[64],  s2 = wsp[128], s3 = wsp[192],
           s4 = wsp[256], s5 = wsp[320], s6 = wsp[384], s7 = wsp[448];
    asm volatile("" ::: "memory");

#define B_STAGE(k)                                                         \
    {                                                                      \
        const float* s_ = src + (size_t)(k) * 4 * H_;                      \
        float* d_ = &buf[(k) & 1][wid * H_];                               \
        stage16(s_,        d_);        stage16(s_ + 256,  d_ + 256);       \
        stage16(s_ + 512,  d_ + 512);  stage16(s_ + 768,  d_ + 768);       \
        stage16(s_ + 1024, d_ + 1024); stage16(s_ + 1280, d_ + 1280);      \
        stage16(s_ + 1536, d_ + 1536); stage16(s_ + 1792, d_ + 1792);      \
    }

    B_STAGE(0); B_STAGE(1);
    float accs[4];
#pragma unroll
    for (int k = 0; k < 4; ++k) {
        if (k < 3) asm volatile("s_waitcnt vmcnt(8)" ::: "memory");
        else       asm volatile("s_waitcnt vmcnt(0)" ::: "memory");
        const float* row = &buf[k & 1][wid * H_];
        float acc;
        {
            float4 a0 = *(const float4*)&row[0 * 256 + lane * 4];
            float4 a1 = *(const float4*)&row[1 * 256 + lane * 4];
            float4 a2 = *(const float4*)&row[2 * 256 + lane * 4];
            float4 a3 = *(const float4*)&row[3 * 256 + lane * 4];
            float4 a4 = *(const float4*)&row[4 * 256 + lane * 4];
            float4 a5 = *(const float4*)&row[5 * 256 + lane * 4];
            float4 a6 = *(const float4*)&row[6 * 256 + lane * 4];
            float4 a7 = *(const float4*)&row[7 * 256 + lane * 4];
            acc = a0.x*s0.x + a0.y*s0.y + a0.z*s0.z + a0.w*s0.w
                + a1.x*s1.x + a1.y*s1.y + a1.z*s1.z + a1.w*s1.w
                + a2.x*s2.x + a2.y*s2.y + a2.z*s2.z + a2.w*s2.w
                + a3.x*s3.x + a3.y*s3.y + a3.z*s3.z + a3.w*s3.w
                + a4.x*s4.x + a4.y*s4.y + a4.z*s4.z + a4.w*s4.w
                + a5.x*s5.x + a5.y*s5.y + a5.z*s5.z + a5.w*s5.w
                + a6.x*s6.x + a6.y*s6.y + a6.z*s6.z + a6.w*s6.w
                + a7.x*s7.x + a7.y*s7.y + a7.z*s7.z + a7.w*s7.w;
        }
#pragma unroll
        for (int off = 32; off >= 1; off >>= 1) acc += __shfl_xor(acc, off, 64);
        accs[k] = acc;
        if (k < 2) B_STAGE(k + 2);
    }
#undef B_STAGE
    if (lane == 0) {
#pragma unroll
        for (int k = 0; k < 4; ++k)
            vT[(size_t)(d0 + k * 4 + wid) * E_ + e] = accs[k];
    }

    // c[e] = b1[e,:].w2sum[e,:] + sum_d b2[e,d]   (ws regs still live)
    if ((bid & 63) == 0 && wid == 0) {
        const float4* bp = (const float4*)(b1 + (size_t)e * H_) + lane;
        float4 q0 = bp[0],   q1 = bp[64],  q2 = bp[128], q3 = bp[192],
               q4 = bp[256], q5 = bp[320], q6 = bp[384], q7 = bp[448];
        float s = q0.x*s0.x + q0.y*s0.y + q0.z*s0.z + q0.w*s0.w
                + q1.x*s1.x + q1.y*s1.y + q1.z*s1.z + q1.w*s1.w
                + q2.x*s2.x + q2.y*s2.y + q2.z*s2.z + q2.w*s2.w
                + q3.x*s3.x + q3.y*s3.y + q3.z*s3.z + q3.w*s3.w
                + q4.x*s4.x + q4.y*s4.y + q4.z*s4.z + q4.w*s4.w
                + q5.x*s5.x + q5.y*s5.y + q5.z*s5.z + q5.w*s5.w
                + q6.x*s6.x + q6.y*s6.y + q6.z*s6.z + q6.w*s6.w
                + q7.x*s7.x + q7.y*s7.y + q7.z*s7.z + q7.w*s7.w;
        const float4* cp = (const float4*)(b2 + (size_t)e * D_) + lane;
#pragma unroll
        for (int j = 0; j < 4; ++j) {
            float4 bb = cp[j * 64];
            s += bb.x + bb.y + bb.z + bb.w;
        }
#pragma unroll
        for (int off = 32; off >= 1; off >>= 1) s += __shfl_xor(s, off, 64);
        if (lane == 0) c[e] = s;
    }
}

// --------------------------------------------------------------------------
// Kernel C (R15's version, now isolated): LDS-staged gating at 2 blocks/CU.
// 512 blocks x 256 thr; block stages wg (32 KB) + vT (32 KB) into LDS once,
// then 4 waves x 2 tokens each, both tokens SHARING each LDS read.
// Conflict-free reads: lane l -> 16B unit at row (l>>1), col group (l&1);
// wave reads 1 KB contiguous LDS. Butterfly over lane bits [5:1].
// --------------------------------------------------------------------------
__global__ __launch_bounds__(256) void token_kernel(
    const float* __restrict__ x,  const float* __restrict__ wg,
    const float* __restrict__ vT, const float* __restrict__ cbuf,
    float* __restrict__ sbuf)
{
    __shared__ float wgl[D_ * E_];   // 32 KB  [d][e]
    __shared__ float vtl[D_ * E_];   // 32 KB  [d][e]
    const int wid = threadIdx.x >> 6, lane = threadIdx.x & 63;

#pragma unroll
    for (int r = 0; r < 8; ++r) {
        int base = r * 1024 + wid * 256;
        stage16(wg + base + lane * 4, wgl + base);
        stage16(vT + base + lane * 4, vtl + base);
    }
    asm volatile("s_waitcnt vmcnt(0)" ::: "memory");
    __syncthreads();

    const int half = lane & 1;       // 0 -> expert cols 0-3, 1 -> cols 4-7
    const int rrow = lane >> 1;      // row residue mod 32

    const int nA = blockIdx.x * 8 + wid * 2;
    const float* xga = x + (size_t)nA * D_ + rrow;
    const float* xgb = xga + D_;

    float agA[4] = {0,0,0,0}, avA[4] = {0,0,0,0};
    float agB[4] = {0,0,0,0}, avB[4] = {0,0,0,0};

#pragma unroll
    for (int k = 0; k < 32; ++k) {
        float xa = xga[32 * k];
        float xb = xgb[32 * k];
        const int o = (32 * k + rrow) * 8 + half * 4;
        float4 w4 = *(const float4*)&wgl[o];
        float4 v4 = *(const float4*)&vtl[o];
        agA[0] += xa * w4.x; agA[1] += xa * w4.y; agA[2] += xa * w4.z; agA[3] += xa * w4.w;
        avA[0] += xa * v4.x; avA[1] += xa * v4.y; avA[2] += xa * v4.z; avA[3] += xa * v4.w;
        agB[0] += xb * w4.x; agB[1] += xb * w4.y; agB[2] += xb * w4.z; agB[3] += xb * w4.w;
        avB[0] += xb * v4.x; avB[1] += xb * v4.y; avB[2] += xb * v4.z; avB[3] += xb * v4.w;
    }

#pragma unroll
    for (int off = 2; off <= 32; off <<= 1) {
#pragma unroll
        for (int q = 0; q < 4; ++q) {
            agA[q] += __shfl_xor(agA[q], off, 64);
            avA[q] += __shfl_xor(avA[q], off, 64);
            agB[q] += __shfl_xor(agB[q], off, 64);
            avB[q] += __shfl_xor(avB[q], off, 64);
        }
    }
    // lane 1 holds expert cols 4-7 of both tokens
    float gA4 = __shfl(agA[0], 1, 64), gA5 = __shfl(agA[1], 1, 64),
          gA6 = __shfl(agA[2], 1, 64), gA7 = __shfl(agA[3], 1, 64);
    float hA4 = __shfl(avA[0], 1, 64), hA5 = __shfl(avA[1], 1, 64),
          hA6 = __shfl(avA[2], 1, 64), hA7 = __shfl(avA[3], 1, 64);
    float gB4 = __shfl(agB[0], 1, 64), gB5 = __shfl(agB[1], 1, 64),
          gB6 = __shfl(agB[2], 1, 64), gB7 = __shfl(agB[3], 1, 64);
    float hB4 = __shfl(avB[0], 1, 64), hB5 = __shfl(avB[1], 1, 64),
          hB6 = __shfl(avB[2], 1, 64), hB7 = __shfl(avB[3], 1, 64);

    if (lane == 0) {
#pragma unroll
        for (int tok = 0; tok < 2; ++tok) {
            float lg[E_], dv[E_];
            if (tok == 0) {
                lg[0]=agA[0]; lg[1]=agA[1]; lg[2]=agA[2]; lg[3]=agA[3];
                lg[4]=gA4;    lg[5]=gA5;    lg[6]=gA6;    lg[7]=gA7;
                dv[0]=avA[0]; dv[1]=avA[1]; dv[2]=avA[2]; dv[3]=avA[3];
                dv[4]=hA4;    dv[5]=hA5;    dv[6]=hA6;    dv[7]=hA7;
            } else {
                lg[0]=agB[0]; lg[1]=agB[1]; lg[2]=agB[2]; lg[3]=agB[3];
                lg[4]=gB4;    lg[5]=gB5;    lg[6]=gB6;    lg[7]=gB7;
                dv[0]=avB[0]; dv[1]=avB[1]; dv[2]=avB[2]; dv[3]=avB[3];
                dv[4]=hB4;    dv[5]=hB5;    dv[6]=hB6;    dv[7]=hB7;
            }
            // top-2, tie -> lower index (jax.lax.top_k semantics)
            float m0 = lg[0]; int i0 = 0;
#pragma unroll
            for (int q = 1; q < E_; ++q) if (lg[q] > m0) { m0 = lg[q]; i0 = q; }
            float m1 = -3.0e38f; int i1 = 0;
#pragma unroll
            for (int q = 0; q < E_; ++q) if (q != i0 && lg[q] > m1) { m1 = lg[q]; i1 = q; }
            float dv0 = 0.f, dv1 = 0.f, c0v = 0.f, c1v = 0.f;
#pragma unroll
            for (int q = 0; q < E_; ++q) {
                if (q == i0) { dv0 += dv[q]; c0v += cbuf[q]; }
                if (q == i1) { dv1 += dv[q]; c1v += cbuf[q]; }
            }
            float g1w = 1.f / (1.f + expf(m0 - m1));
            sbuf[nA + tok] = (1.f - g1w) * (dv0 + c0v) + g1w * (dv1 + c1v);
        }
    }
}

// --------------------------------------------------------------------------
// Kernel D (round-8 verbatim): out[b,t] = s[b,t] - logsumexp_t(s[b,:]).
// One block, 4 waves, wave per batch row; 16 values per lane.
// --------------------------------------------------------------------------
__global__ __launch_bounds__(256) void lsm_kernel(const float* __restrict__ s,
                                                  float* __restrict__ out) {
    int brow = threadIdx.x >> 6;
    int lane = threadIdx.x & 63;
    const float* row = s + (size_t)brow * T_;
    float vals[16];
    float mx = -3.0e38f;
#pragma unroll
    for (int k = 0; k < 16; ++k) {
        vals[k] = row[lane + 64 * k];
        mx = fmaxf(mx, vals[k]);
    }
#pragma unroll
    for (int off = 32; off >= 1; off >>= 1) mx = fmaxf(mx, __shfl_xor(mx, off, 64));
    float sm = 0.f;
#pragma unroll
    for (int k = 0; k < 16; ++k) sm += expf(vals[k] - mx);
#pragma unroll
    for (int off = 32; off >= 1; off >>= 1) sm += __shfl_xor(sm, off, 64);
    float lse = mx + logf(sm);
#pragma unroll
    for (int k = 0; k < 16; ++k) out[(size_t)brow * T_ + lane + 64 * k] = vals[k] - lse;
}

// ---------------------------------------------------------------------------
extern "C" void kernel_launch(void* const* d_in, const int* in_sizes, int n_in,
                              void* d_out, int out_size, void* d_ws, size_t ws_size,
                              hipStream_t stream) {
    const float* x  = (const float*)d_in[0];   // [B, T, D]
    const float* wg = (const float*)d_in[1];   // [D, E]
    const float* w1 = (const float*)d_in[2];   // [E, D, H]
    const float* b1 = (const float*)d_in[3];   // [E, H]
    const float* w2 = (const float*)d_in[4];   // [E, H, D]
    const float* b2 = (const float*)d_in[5];   // [E, D]
    float* out = (float*)d_out;                // [B, T]

    float* ws     = (float*)d_ws;
    float* w2sum  = ws;                        // E*H = 16384 floats
    float* vT     = ws + 16384;                // D*E =  8192 floats ([d][e])
    float* cbuf   = ws + 24576;                // E
    float* sbuf   = ws + 24592;                // N = 4096

    // A: 16384 rows, 32 rows/block (8-tile rolling pipeline) -> 512 blocks
    w2sum_kernel<<<dim3(512), dim3(256), 0, stream>>>(w2, w2sum);
    // B: 8192 rows, 16 rows/block (4-tile rolling pipeline) -> 512 blocks
    v_build_kernel<<<dim3(512), dim3(256), 0, stream>>>(w1, w2sum, b1, b2, vT, cbuf);
    // C: 4096 tokens, 8/block (2/wave, shared LDS reads) -> 512 blocks
    token_kernel<<<dim3(512), dim3(256), 0, stream>>>(x, wg, vT, cbuf, sbuf);
    // D: log-softmax over T per batch row, single block
    lsm_kernel<<<dim3(1), dim3(256), 0, stream>>>(sbuf, out);
}